// Round 3
// baseline (158.074 us; speedup 1.0000x reference)
//
#include <hip/hip_runtime.h>

#define BATCH 32768
#define DIM   256
#define NEXP  8
#define MT    32          // rows per tile
#define STRIDE 264        // DIM + 8 bf16 pad (measured 0 bank conflicts)

typedef __bf16 bf16x8 __attribute__((ext_vector_type(8)));
typedef __bf16 bf16x4 __attribute__((ext_vector_type(4)));
typedef float  f32x16 __attribute__((ext_vector_type(16)));

static __device__ __forceinline__ float sigmoid_f(float x) {
    return __builtin_amdgcn_rcpf(1.f + __expf(-x));
}
static __device__ __forceinline__ float tanh_f(float x) {
    return 1.f - 2.f * __builtin_amdgcn_rcpf(__expf(2.f * x) + 1.f);
}
static __device__ __forceinline__ unsigned short f2b(float x) {
    union { __bf16 b; unsigned short u; } v; v.b = (__bf16)x; return v.u;
}

// ---- fused prep: blocks 0..511 convert W1/W2 fp32->bf16; blocks 512..639
// scatter sample indices into fixed per-expert regions idxb[e*BATCH + ...]
__global__ void prep_kernel(const float4* __restrict__ W1, const float4* __restrict__ W2,
                            const float* __restrict__ t,
                            ushort4* __restrict__ W1b, ushort4* __restrict__ W2b,
                            int* __restrict__ cursor, int* __restrict__ idxb) {
    const int b = blockIdx.x;
    if (b < 512) {
        const int i = b * 256 + threadIdx.x;
        const float4 a = W1[i];
        const float4 c = W2[i];
        W1b[i] = make_ushort4(f2b(a.x), f2b(a.y), f2b(a.z), f2b(a.w));
        W2b[i] = make_ushort4(f2b(c.x), f2b(c.y), f2b(c.z), f2b(c.w));
    } else {
        __shared__ int h[NEXP], base[NEXP];
        if (threadIdx.x < NEXP) h[threadIdx.x] = 0;
        __syncthreads();
        const int i = (b - 512) * 256 + threadIdx.x;
        const int e = min((int)(t[i] * 8.0f), NEXP - 1);
        const int lr = atomicAdd(&h[e], 1);
        __syncthreads();
        if (threadIdx.x < NEXP)
            base[threadIdx.x] = atomicAdd(&cursor[threadIdx.x], h[threadIdx.x]);
        __syncthreads();
        idxb[e * BATCH + base[e] + lr] = i;
    }
}

// ---- grouped fused 2-layer MLP, double-buffered + software-pipelined
__global__ void __launch_bounds__(256, 2)
mlp_kernel(const float* __restrict__ y,
           const float* __restrict__ scales,
           const float* __restrict__ shifta,
           const float* __restrict__ shiftb,
           const float* __restrict__ b1,
           const float* __restrict__ b2,
           const unsigned short* __restrict__ W1b,
           const unsigned short* __restrict__ W2b,
           const int* __restrict__ cnt,
           const int* __restrict__ idxb,
           float* __restrict__ out) {
    __shared__ __bf16 ab[2][MT * STRIDE];   // y tile (bf16) then tanh(h), x2 buffers
    __shared__ int rows[2][MT];

    const int tx   = threadIdx.x;
    const int wave = tx >> 6;
    const int lane = tx & 63;
    const int nl   = lane & 31;
    const int kh   = lane >> 5;
    const int nbase = wave * 64;

    int c[NEXP], tp[NEXP + 1];
    tp[0] = 0;
#pragma unroll
    for (int e = 0; e < NEXP; ++e) {
        c[e] = cnt[e];
        tp[e + 1] = tp[e] + ((c[e] + MT - 1) >> 5);
    }
    const int total = tp[NEXP];

    const float sa = sigmoid_f(shifta[0]);
    const float sb = sigmoid_f(shiftb[0]);
    const float av = -sa;
    const float bvv = sb;
    const float k1 = 0.5f * (bvv - av);
    const float k2 = 0.5f * (av + bvv);
    const bool needy = (k2 != 0.0f);

    int tile = blockIdx.x;
    if (tile >= total) return;

    // ctx of a tile
    auto get_ctx = [&](int tl, int& e_, int& rb_, int& nr_) {
        int e = 0;
#pragma unroll
        for (int j = 0; j < NEXP; ++j) if (tl >= tp[j + 1]) e = j + 1;
        e_  = e;
        rb_ = (tl - tp[e]) * MT;
        nr_ = min(MT, c[e] - rb_);
    };

    int e, rbase, nrows;
    get_ctx(tile, e, rbase, nrows);

    // ---- prologue: stage tile into buf 0
    {
        const int* idx_e = idxb + e * BATCH;
#pragma unroll
        for (int p = 0; p < 8; ++p) {
            const int r  = p * 4 + wave;
            const int rr = min(r, nrows - 1);
            const int g  = idx_e[rbase + rr];
            if (lane == 0) rows[0][r] = (r < nrows) ? g : -1;
            const float4 v = *(const float4*)(y + (long)g * DIM + lane * 4);
            bf16x4 w;
            w[0] = (__bf16)v.x; w[1] = (__bf16)v.y; w[2] = (__bf16)v.z; w[3] = (__bf16)v.w;
            *(bf16x4*)(ab[0] + r * STRIDE + lane * 4) = w;
        }
    }

    int buf = 0;
    while (true) {
        const int ntile = tile + gridDim.x;
        const bool hasn = ntile < total;
        int ne, nrbase, nnrows;
        get_ctx(hasn ? ntile : tile, ne, nrbase, nnrows);

        // ---- idx prefetch for next tile (hidden under GEMM1)
        int g_pf[8];
        {
            const int* idx_n = idxb + ne * BATCH;
#pragma unroll
            for (int p = 0; p < 8; ++p) {
                const int r  = p * 4 + wave;
                const int rr = min(r, nnrows - 1);
                g_pf[p] = idx_n[nrbase + rr];
            }
        }

        __syncthreads();   // (a) staging of `buf` visible; all waves done prev GEMM2

        const __bf16* apt = ab[buf] + nl * STRIDE + kh * 8;

        // ---- GEMM1: full B preload burst, then MFMA
        {
            const unsigned short* w1p = W1b + (((e << 8) | (nbase + nl)) << 8) + (kh << 3);
            bf16x8 bw[16][2];
#pragma unroll
            for (int ks = 0; ks < 16; ++ks)
#pragma unroll
                for (int ni = 0; ni < 2; ++ni)
                    bw[ks][ni] = *(const bf16x8*)(w1p + ni * (32 * 256) + ks * 16);
            f32x16 acc[2] = {};
#pragma unroll
            for (int ks = 0; ks < 16; ++ks) {
                bf16x8 a = *(const bf16x8*)(apt + ks * 16);
#pragma unroll
                for (int ni = 0; ni < 2; ++ni)
                    acc[ni] = __builtin_amdgcn_mfma_f32_32x32x16_bf16(a, bw[ks][ni], acc[ni], 0, 0, 0);
            }

            __syncthreads();   // (b) all GEMM1 reads of buf done

            // ---- y-row prefetch for next tile (hidden under tanh)
            float4 v_pf[8];
#pragma unroll
            for (int p = 0; p < 8; ++p)
                v_pf[p] = *(const float4*)(y + (long)g_pf[p] * DIM + lane * 4);

            // ---- tanh(h + b1) -> ab[buf]
#pragma unroll
            for (int ni = 0; ni < 2; ++ni) {
                const int n = nbase + ni * 32 + nl;
                const float b1v = b1[(e << 8) | n];
#pragma unroll
                for (int r = 0; r < 16; ++r) {
                    const int row = (r & 3) + ((r >> 2) << 3) + (kh << 2);
                    ab[buf][row * STRIDE + n] = (__bf16)tanh_f(acc[ni][r] + b1v);
                }
            }

            __syncthreads();   // (c) tanh writes visible

            // ---- stage next tile into buf^1 (safe: all waves past (a))
#pragma unroll
            for (int p = 0; p < 8; ++p) {
                const int r = p * 4 + wave;
                if (lane == 0) rows[buf ^ 1][r] = (hasn && r < nnrows) ? g_pf[p] : -1;
                bf16x4 w;
                w[0] = (__bf16)v_pf[p].x; w[1] = (__bf16)v_pf[p].y;
                w[2] = (__bf16)v_pf[p].z; w[3] = (__bf16)v_pf[p].w;
                *(bf16x4*)(ab[buf ^ 1] + r * STRIDE + lane * 4) = w;
            }
        }

        // ---- GEMM2: full B preload burst, then MFMA
        f32x16 acc2[2] = {};
        {
            const unsigned short* w2p = W2b + (((e << 8) | (nbase + nl)) << 8) + (kh << 3);
            bf16x8 bw[16][2];
#pragma unroll
            for (int ks = 0; ks < 16; ++ks)
#pragma unroll
                for (int ni = 0; ni < 2; ++ni)
                    bw[ks][ni] = *(const bf16x8*)(w2p + ni * (32 * 256) + ks * 16);
#pragma unroll
            for (int ks = 0; ks < 16; ++ks) {
                bf16x8 a = *(const bf16x8*)(apt + ks * 16);
#pragma unroll
                for (int ni = 0; ni < 2; ++ni)
                    acc2[ni] = __builtin_amdgcn_mfma_f32_32x32x16_bf16(a, bw[ks][ni], acc2[ni], 0, 0, 0);
            }
        }

        // ---- epilogue: out = k1*sig(scales)*(f+b2) + k2*y
#pragma unroll
        for (int ni = 0; ni < 2; ++ni) {
            const int n = nbase + ni * 32 + nl;
            const float c1  = k1 * sigmoid_f(scales[n]);
            const float b2v = b2[(e << 8) | n];
#pragma unroll
            for (int r = 0; r < 16; ++r) {
                const int row = (r & 3) + ((r >> 2) << 3) + (kh << 2);
                const int g = rows[buf][row];
                if (g >= 0) {
                    float res = c1 * (acc2[ni][r] + b2v);
                    if (needy) res += k2 * y[(long)g * DIM + n];
                    out[(long)g * DIM + n] = res;
                }
            }
        }

        if (!hasn) break;
        tile = ntile; e = ne; rbase = nrbase; nrows = nnrows; buf ^= 1;
    }
}

extern "C" void kernel_launch(void* const* d_in, const int* in_sizes, int n_in,
                              void* d_out, int out_size, void* d_ws, size_t ws_size,
                              hipStream_t stream) {
    const float* t      = (const float*)d_in[0];
    const float* y      = (const float*)d_in[1];
    const float* W1     = (const float*)d_in[2];
    const float* b1     = (const float*)d_in[3];
    const float* W2     = (const float*)d_in[4];
    const float* b2     = (const float*)d_in[5];
    const float* scales = (const float*)d_in[6];
    const float* shifta = (const float*)d_in[7];
    const float* shiftb = (const float*)d_in[8];
    float* out = (float*)d_out;

    char* ws = (char*)d_ws;
    int* cursor = (int*)ws;                               // [8]
    int* idxb   = (int*)(ws + 256);                       // [8][32768]
    unsigned short* W1b = (unsigned short*)(ws + 256 + NEXP * BATCH * 4);
    unsigned short* W2b = W1b + NEXP * DIM * DIM;

    hipMemsetAsync(cursor, 0, 32, stream);
    prep_kernel<<<640, 256, 0, stream>>>((const float4*)W1, (const float4*)W2, t,
                                         (ushort4*)W1b, (ushort4*)W2b, cursor, idxb);
    mlp_kernel<<<512, 256, 0, stream>>>(y, scales, shifta, shiftb, b1, b2,
                                        W1b, W2b, cursor, idxb, out);
}

// Round 4
// 133.047 us; speedup vs baseline: 1.1881x; 1.1881x over previous
//
#include <hip/hip_runtime.h>

#define BATCH 32768
#define DIM   256
#define NEXP  8
#define MT    32          // rows per tile
#define STRIDE 264        // DIM + 8 bf16 pad (measured 0 bank conflicts)

typedef __bf16 bf16x8 __attribute__((ext_vector_type(8)));
typedef __bf16 bf16x4 __attribute__((ext_vector_type(4)));
typedef float  f32x16 __attribute__((ext_vector_type(16)));

static __device__ __forceinline__ float sigmoid_f(float x) {
    return __builtin_amdgcn_rcpf(1.f + __expf(-x));
}
static __device__ __forceinline__ float tanh_f(float x) {
    return 1.f - 2.f * __builtin_amdgcn_rcpf(__expf(2.f * x) + 1.f);
}

// ---- fused prep.
// Blocks 0..255: pack W1/W2 fp32 -> bf16 in MFMA-B-fragment order:
//   pk[e][nt][ks][kh][nl][j] = W[e][nt*32+nl][ks*16+kh*8+j]
// so a wave's B-frag load (lane=(kh<<5)|nl, 16B) is one contiguous 1KB line.
// Blocks 256..383: scatter sample indices into per-expert regions.
__global__ void prep_kernel(const float* __restrict__ W1, const float* __restrict__ W2,
                            const float* __restrict__ t,
                            bf16x8* __restrict__ W1p, bf16x8* __restrict__ W2p,
                            int* __restrict__ cursor, int* __restrict__ idxb) {
    const int b = blockIdx.x;
    if (b < 256) {
        // tuple id: (((e*8+nt)*16+ks)*2+kh)*32+nl   (65536 total)
        const int tid = b * 256 + threadIdx.x;
        const int nl = tid & 31;
        const int kh = (tid >> 5) & 1;
        const int ks = (tid >> 6) & 15;
        const int entt = tid >> 10;            // e*8+nt
        const int col = ((entt & 7) << 5) | nl;
        const int e   = entt >> 3;
        const long src = ((long)(e << 8 | col) << 8) + (ks << 4) + (kh << 3);
        const float4 a0 = *(const float4*)(W1 + src);
        const float4 a1 = *(const float4*)(W1 + src + 4);
        const float4 c0 = *(const float4*)(W2 + src);
        const float4 c1 = *(const float4*)(W2 + src + 4);
        bf16x8 w1, w2;
        w1[0] = (__bf16)a0.x; w1[1] = (__bf16)a0.y; w1[2] = (__bf16)a0.z; w1[3] = (__bf16)a0.w;
        w1[4] = (__bf16)a1.x; w1[5] = (__bf16)a1.y; w1[6] = (__bf16)a1.z; w1[7] = (__bf16)a1.w;
        w2[0] = (__bf16)c0.x; w2[1] = (__bf16)c0.y; w2[2] = (__bf16)c0.z; w2[3] = (__bf16)c0.w;
        w2[4] = (__bf16)c1.x; w2[5] = (__bf16)c1.y; w2[6] = (__bf16)c1.z; w2[7] = (__bf16)c1.w;
        W1p[tid] = w1;      // 16B per lane, lane-consecutive -> coalesced
        W2p[tid] = w2;
    } else {
        __shared__ int h[NEXP], base[NEXP];
        if (threadIdx.x < NEXP) h[threadIdx.x] = 0;
        __syncthreads();
        const int i = (b - 256) * 256 + threadIdx.x;
        const int e = min((int)(t[i] * 8.0f), NEXP - 1);
        const int lr = atomicAdd(&h[e], 1);
        __syncthreads();
        if (threadIdx.x < NEXP)
            base[threadIdx.x] = atomicAdd(&cursor[threadIdx.x], h[threadIdx.x]);
        __syncthreads();
        idxb[e * BATCH + base[e] + lr] = i;
    }
}

// ---- grouped fused 2-layer MLP. MT=32 rows/tile, ~1 tile per block,
// 4 blocks/CU. Wave: 32 rows x 64 cols (2 mfma_32x32x16 acc tiles).
__global__ void __launch_bounds__(256, 4)
mlp_kernel(const float* __restrict__ y,
           const float* __restrict__ scales,
           const float* __restrict__ shifta,
           const float* __restrict__ shiftb,
           const float* __restrict__ b1,
           const float* __restrict__ b2,
           const bf16x8* __restrict__ W1p,
           const bf16x8* __restrict__ W2p,
           const int* __restrict__ cnt,
           const int* __restrict__ idxb,
           float* __restrict__ out) {
    __shared__ __bf16 ab[MT * STRIDE];   // y tile (bf16), then tanh(h)
    __shared__ int rows[MT];

    const int tx   = threadIdx.x;
    const int wave = tx >> 6;
    const int lane = tx & 63;
    const int nl   = lane & 31;
    const int kh   = lane >> 5;
    const int nbase = wave * 64;

    int c[NEXP], tp[NEXP + 1];
    tp[0] = 0;
#pragma unroll
    for (int e = 0; e < NEXP; ++e) {
        c[e] = cnt[e];
        tp[e + 1] = tp[e] + ((c[e] + MT - 1) >> 5);
    }
    const int total = tp[NEXP];

    const float sa = sigmoid_f(shifta[0]);
    const float sb = sigmoid_f(shiftb[0]);
    const float av = -sa;
    const float bvv = sb;
    const float k1 = 0.5f * (bvv - av);
    const float k2 = 0.5f * (av + bvv);
    const bool needy = (k2 != 0.0f);    // with given inputs k2==0 exactly

    for (int tile = blockIdx.x; tile < total; tile += gridDim.x) {
        int e = 0;
#pragma unroll
        for (int j = 0; j < NEXP; ++j) if (tile >= tp[j + 1]) e = j + 1;
        const int rbase = (tile - tp[e]) * MT;
        const int nrows = min(MT, c[e] - rbase);
        const int* idx_e = idxb + e * BATCH;

        __syncthreads();   // previous iteration's readers of ab/rows done
        // stage gathered y rows -> bf16 LDS tile; one row per wave per pass
#pragma unroll
        for (int pass = 0; pass < 8; ++pass) {
            const int r  = pass * 4 + wave;
            const int rr = min(r, nrows - 1);
            const int g  = idx_e[rbase + rr];
            if (lane == 0) rows[r] = (r < nrows) ? g : -1;
            const float4 v = *(const float4*)(y + (long)g * DIM + lane * 4);
            bf16x4 w;
            w[0] = (__bf16)v.x; w[1] = (__bf16)v.y; w[2] = (__bf16)v.z; w[3] = (__bf16)v.w;
            *(bf16x4*)(ab + r * STRIDE + lane * 4) = w;
        }
        __syncthreads();

        const __bf16* apt = ab + nl * STRIDE + kh * 8;

        // ---- GEMM1: h = y @ W1[e]^T  (A from LDS, B packed-coalesced from L2)
        // frag index for (nt, ks): ((e*8+nt)*16+ks)*64 + lane   [bf16x8 units]
        const bf16x8* w1p = W1p + ((e << 3) << 10) + (((nbase >> 5) << 10)) + lane;
        f32x16 acc[2] = {};
#pragma unroll
        for (int ks = 0; ks < 16; ++ks) {
            bf16x8 a = *(const bf16x8*)(apt + ks * 16);
#pragma unroll
            for (int ni = 0; ni < 2; ++ni) {
                bf16x8 bb = w1p[(ni << 10) + (ks << 6)];
                acc[ni] = __builtin_amdgcn_mfma_f32_32x32x16_bf16(a, bb, acc[ni], 0, 0, 0);
            }
        }
        __syncthreads();   // all GEMM1 reads of ab complete

        // ---- tanh(h + b1) -> ab (C/D layout: col=lane&31, row=(r&3)+8*(r>>2)+4*kh)
#pragma unroll
        for (int ni = 0; ni < 2; ++ni) {
            const int n = nbase + ni * 32 + nl;
            const float b1v = b1[(e << 8) | n];
#pragma unroll
            for (int r = 0; r < 16; ++r) {
                const int row = (r & 3) + ((r >> 2) << 3) + (kh << 2);
                ab[row * STRIDE + n] = (__bf16)tanh_f(acc[ni][r] + b1v);
            }
        }
        __syncthreads();

        // ---- GEMM2: f = h @ W2[e]^T
        const bf16x8* w2p = W2p + ((e << 3) << 10) + (((nbase >> 5) << 10)) + lane;
        f32x16 acc2[2] = {};
#pragma unroll
        for (int ks = 0; ks < 16; ++ks) {
            bf16x8 a = *(const bf16x8*)(apt + ks * 16);
#pragma unroll
            for (int ni = 0; ni < 2; ++ni) {
                bf16x8 bb = w2p[(ni << 10) + (ks << 6)];
                acc2[ni] = __builtin_amdgcn_mfma_f32_32x32x16_bf16(a, bb, acc2[ni], 0, 0, 0);
            }
        }

        // ---- epilogue: out = k1*sig(scales)*(f+b2) + k2*y
#pragma unroll
        for (int ni = 0; ni < 2; ++ni) {
            const int n = nbase + ni * 32 + nl;
            const float c1  = k1 * sigmoid_f(scales[n]);
            const float b2v = b2[(e << 8) | n];
#pragma unroll
            for (int r = 0; r < 16; ++r) {
                const int row = (r & 3) + ((r >> 2) << 3) + (kh << 2);
                const int g = rows[row];
                if (g >= 0) {
                    float res = c1 * (acc2[ni][r] + b2v);
                    if (needy) res += k2 * y[(long)g * DIM + n];
                    out[(long)g * DIM + n] = res;
                }
            }
        }
    }
}

extern "C" void kernel_launch(void* const* d_in, const int* in_sizes, int n_in,
                              void* d_out, int out_size, void* d_ws, size_t ws_size,
                              hipStream_t stream) {
    const float* t      = (const float*)d_in[0];
    const float* y      = (const float*)d_in[1];
    const float* W1     = (const float*)d_in[2];
    const float* b1     = (const float*)d_in[3];
    const float* W2     = (const float*)d_in[4];
    const float* b2     = (const float*)d_in[5];
    const float* scales = (const float*)d_in[6];
    const float* shifta = (const float*)d_in[7];
    const float* shiftb = (const float*)d_in[8];
    float* out = (float*)d_out;

    char* ws = (char*)d_ws;
    int* cursor = (int*)ws;                               // [8]
    int* idxb   = (int*)(ws + 256);                       // [8][32768]
    bf16x8* W1p = (bf16x8*)(ws + 256 + NEXP * BATCH * 4); // packed 1MB
    bf16x8* W2p = W1p + 65536;

    hipMemsetAsync(cursor, 0, 32, stream);
    prep_kernel<<<384, 256, 0, stream>>>(W1, W2, t, W1p, W2p, cursor, idxb);
    mlp_kernel<<<1032, 256, 0, stream>>>(y, scales, shifta, shiftb, b1, b2,
                                         W1p, W2p, cursor, idxb, out);
}